// Round 5
// baseline (587.563 us; speedup 1.0000x reference)
//
#include <hip/hip_runtime.h>
#include <hip/hip_cooperative_groups.h>

namespace cg = cooperative_groups;

#define NEG_SLOPE 0.01f
#define ETA 0.5f
#define NEG_BIG -3.402823466e38f
#define LOG2E 1.4426950408889634f
#define PCHUNK 4096   // edges per partition virtual-block
#define CAP 5504      // per-bucket capacity (mean 4096 + 22 sigma)

typedef _Float16 half2v __attribute__((ext_vector_type(2)));
typedef _Float16 half8v __attribute__((ext_vector_type(8)));
typedef float f32x4v __attribute__((ext_vector_type(4)));

#if defined(__has_builtin)
#if __has_builtin(__builtin_amdgcn_fdot2)
#define HAVE_FDOT2 1
#endif
#if __has_builtin(__builtin_amdgcn_exp2f)
#define HAVE_EXP2 1
#endif
#if __has_builtin(__builtin_amdgcn_update_dpp)
#define HAVE_DPP 1
#endif
#if __has_builtin(__builtin_amdgcn_mfma_f32_16x16x32_f16)
#define HAVE_MFMA16 1
#endif
#endif

__device__ __forceinline__ float fdot2(half2v a, half2v b, float c) {
#ifdef HAVE_FDOT2
  return __builtin_amdgcn_fdot2(a, b, c, false);
#else
  return (float)a[0] * (float)b[0] + (float)a[1] * (float)b[1] + c;
#endif
}

__device__ __forceinline__ unsigned pack2(float x, float y) {
  half2v h = {( _Float16)x, (_Float16)y};
  return __builtin_bit_cast(unsigned, h);
}

__device__ __forceinline__ float fexp2(float x) {
#ifdef HAVE_EXP2
  return __builtin_amdgcn_exp2f(x);
#else
  return __expf(x * 0.6931471805599453f);
#endif
}

// Interleaved dual 16-lane row-sum (VALU pipe, no LDS).
__device__ __forceinline__ void rowsum16x2(float& x, float& y) {
#ifdef HAVE_DPP
#define DPPADD(v, ctl)                                                        \
  v += __builtin_bit_cast(float, __builtin_amdgcn_update_dpp(                 \
         0, __builtin_bit_cast(int, v), ctl, 0xf, 0xf, true))
  DPPADD(x, 0x121); DPPADD(y, 0x121);   // row_ror:1
  DPPADD(x, 0x122); DPPADD(y, 0x122);   // row_ror:2
  DPPADD(x, 0x124); DPPADD(y, 0x124);   // row_ror:4
  DPPADD(x, 0x128); DPPADD(y, 0x128);   // row_ror:8
#undef DPPADD
#else
#pragma unroll
  for (int o = 1; o < 16; o <<= 1) {
    x += __shfl_xor(x, o);
    y += __shfl_xor(y, o);
  }
#endif
}

// ---- prep: node dots af/bf (pre-scaled by log2e) + interleaved f16 record ----
__device__ __forceinline__ void prep_body(const float* __restrict__ h,
                                          const float* __restrict__ tax,
                                          const float* __restrict__ whw,
                                          float* __restrict__ af, float* __restrict__ bf,
                                          uint4* __restrict__ rec, int n, int blk) {
  int gid = blk * 256 + (int)threadIdx.x;
  int node = gid >> 4, lane = gid & 15;
  if (node >= n) return;  // device-fn return: safe (no syncthreads below)
  float4 x  = ((const float4*)(h + (size_t)node * 64))[lane];
  float4 tx = ((const float4*)(tax + (size_t)node * 64))[lane];
  float4 wa = ((const float4*)whw)[lane];
  float4 wb = ((const float4*)(whw + 64))[lane];
  uint4 r;
  r.x = pack2(tx.x, tx.y);
  r.y = pack2(tx.z, tx.w);
  r.z = pack2(x.x, x.y);
  r.w = pack2(x.z, x.w);
  rec[((size_t)node << 4) + lane] = r;
  float pa = x.x * wa.x + x.y * wa.y + x.z * wa.z + x.w * wa.w;
  float pb = x.x * wb.x + x.y * wb.y + x.z * wb.z + x.w * wb.w;
#pragma unroll
  for (int o = 8; o; o >>= 1) {
    pa += __shfl_xor(pa, o);
    pb += __shfl_xor(pb, o);
  }
  // leaky_relu(c*x) == c*leaky_relu(x) for c>0: exp2-domain prescale is exact.
  if (lane == 0) { af[node] = pa * LOG2E; bf[node] = pb * LOG2E; }
}

// ---- partition by bucket = dst>>8 ----
// LDS reuse across sequential calls is safe: the first __syncthreads separates
// this call's s_hist writes from the previous call's scatter (distinct arrays).
__device__ __forceinline__ void part_body(const int* __restrict__ src,
                                          const int* __restrict__ dst,
                                          int* __restrict__ gcur, int* __restrict__ pck,
                                          int ne, int blk) {
  __shared__ int s_hist[512];
  __shared__ int s_res[512];
  __shared__ int s_cur[512];
  int t = threadIdx.x;
  int base = blk * PCHUNK;
  int cnt = ne - base; if (cnt > PCHUNK) cnt = PCHUNK;
  s_hist[t] = 0; s_hist[t + 256] = 0;
  __syncthreads();
  int i = t * 4;
  for (; i + 3 < cnt; i += 1024) {
    int4 dd = *(const int4*)(dst + base + i);
    atomicAdd(&s_hist[dd.x >> 8], 1);
    atomicAdd(&s_hist[dd.y >> 8], 1);
    atomicAdd(&s_hist[dd.z >> 8], 1);
    atomicAdd(&s_hist[dd.w >> 8], 1);
  }
  for (; i < cnt; ++i) atomicAdd(&s_hist[dst[base + i] >> 8], 1);
  __syncthreads();
  int v0 = s_hist[t], v1 = s_hist[t + 256];
  if (v0 > 0) s_res[t] = atomicAdd(&gcur[t], v0);
  if (v1 > 0) s_res[t + 256] = atomicAdd(&gcur[t + 256], v1);
  s_cur[t] = 0; s_cur[t + 256] = 0;
  __syncthreads();
  i = t * 4;
  for (; i + 3 < cnt; i += 1024) {
    int4 dd = *(const int4*)(dst + base + i);
    int4 ss = *(const int4*)(src + base + i);
    int r, g;
    r = dd.x >> 8; g = s_res[r] + atomicAdd(&s_cur[r], 1);
    if (g < CAP) pck[(size_t)r * CAP + g] = (ss.x << 8) | (dd.x & 255);
    r = dd.y >> 8; g = s_res[r] + atomicAdd(&s_cur[r], 1);
    if (g < CAP) pck[(size_t)r * CAP + g] = (ss.y << 8) | (dd.y & 255);
    r = dd.z >> 8; g = s_res[r] + atomicAdd(&s_cur[r], 1);
    if (g < CAP) pck[(size_t)r * CAP + g] = (ss.z << 8) | (dd.z & 255);
    r = dd.w >> 8; g = s_res[r] + atomicAdd(&s_cur[r], 1);
    if (g < CAP) pck[(size_t)r * CAP + g] = (ss.w << 8) | (dd.w & 255);
  }
  for (; i < cnt; ++i) {
    int d = dst[base + i];
    int r = d >> 8;
    int g = s_res[r] + atomicAdd(&s_cur[r], 1);
    if (g < CAP) pck[(size_t)r * CAP + g] = (src[base + i] << 8) | (d & 255);
  }
}

// One virtual block per 256-dst bucket: exact CSR via LDS hist + scan.
__device__ __forceinline__ void fine_body(const int* __restrict__ pck,
                                          const int* __restrict__ gcur,
                                          int* __restrict__ off, int* __restrict__ srcs,
                                          int n, int nb, int b) {
  __shared__ int s_hist[256];
  __shared__ int s_scan[256];
  __shared__ int s_cur[256];
  __shared__ int s_red[256];
  int t = threadIdx.x;
  int cnt = gcur[b];
  size_t gbase = (size_t)b * CAP;
  int r0 = (t < b) ? gcur[t] : 0;
  int r1 = (t + 256 < b) ? gcur[t + 256] : 0;
  s_red[t] = r0 + r1;
  s_hist[t] = 0;
  __syncthreads();
  for (int s = 128; s; s >>= 1) {
    if (t < s) s_red[t] += s_red[t + s];
    __syncthreads();
  }
  int base = s_red[0];
  int i = t;
  for (; i + 768 < cnt; i += 1024) {
    int p0 = pck[gbase + i];
    int p1 = pck[gbase + i + 256];
    int p2 = pck[gbase + i + 512];
    int p3 = pck[gbase + i + 768];
    atomicAdd(&s_hist[p0 & 255], 1);
    atomicAdd(&s_hist[p1 & 255], 1);
    atomicAdd(&s_hist[p2 & 255], 1);
    atomicAdd(&s_hist[p3 & 255], 1);
  }
  for (; i < cnt; i += 256) atomicAdd(&s_hist[pck[gbase + i] & 255], 1);
  __syncthreads();
  int v = s_hist[t];
  s_scan[t] = v;
  __syncthreads();
  for (int s = 1; s < 256; s <<= 1) {
    int a = (t >= s) ? s_scan[t - s] : 0;
    __syncthreads();
    s_scan[t] += a;
    __syncthreads();
  }
  int pex = s_scan[t] - v;
  int d0 = (b << 8) + t;
  if (d0 < n) off[d0] = base + pex;
  if (b == nb - 1 && t == 0) off[n] = base + cnt;
  s_cur[t] = pex;
  __syncthreads();
  i = t;
  for (; i + 768 < cnt; i += 1024) {
    int p0 = pck[gbase + i];
    int p1 = pck[gbase + i + 256];
    int p2 = pck[gbase + i + 512];
    int p3 = pck[gbase + i + 768];
    int k0 = atomicAdd(&s_cur[p0 & 255], 1);
    srcs[base + k0] = p0 >> 8;
    int k1 = atomicAdd(&s_cur[p1 & 255], 1);
    srcs[base + k1] = p1 >> 8;
    int k2 = atomicAdd(&s_cur[p2 & 255], 1);
    srcs[base + k2] = p2 >> 8;
    int k3 = atomicAdd(&s_cur[p3 & 255], 1);
    srcs[base + k3] = p3 >> 8;
  }
  for (; i < cnt; i += 256) {
    int p = pck[gbase + i];
    int k = atomicAdd(&s_cur[p & 255], 1);
    srcs[base + k] = p >> 8;
  }
}

// One 16-lane group per dst node (16 nodes per 256-thread virtual block),
// pair-unrolled 3-stage software pipeline (8 rec-gathers in flight/wave).
__device__ __forceinline__ void fused_body(const uint4* __restrict__ rec,
                                           const float* __restrict__ af,
                                           const float* __restrict__ bf,
                                           const int* __restrict__ off,
                                           const int* __restrict__ srcs,
                                           unsigned short* __restrict__ z,
                                           int n, int vb) {
  int d = vb * 16 + ((int)threadIdx.x >> 4);
  int q = threadIdx.x & 15;
  if (d >= n) return;  // device-fn return: safe (no syncthreads below)
  uint2 rd = *(const uint2*)((const char*)rec + ((((size_t)d << 4) + q) << 4));
  half2v d01 = __builtin_bit_cast(half2v, rd.x);
  half2v d23 = __builtin_bit_cast(half2v, rd.y);
  float bfd = bf[d];
  int beg = off[d], end = off[d + 1];
  float sf = 0.f, st = 0.f, mt = NEG_BIG;
  float zf0 = 0.f, zf1 = 0.f, zf2 = 0.f, zf3 = 0.f;
  float zt0 = 0.f, zt1 = 0.f, zt2 = 0.f, zt3 = 0.f;
  int s0 = (beg     < end) ? srcs[beg]     : 0;
  int s1 = (beg + 1 < end) ? srcs[beg + 1] : 0;
  uint4 r0 = rec[((size_t)s0 << 4) + q];
  float a0 = af[s0];
  uint4 r1 = rec[((size_t)s1 << 4) + q];
  float a1 = af[s1];
  int s2 = (beg + 2 < end) ? srcs[beg + 2] : 0;
  int s3 = (beg + 3 < end) ? srcs[beg + 3] : 0;
  for (int i = beg; i < end; i += 2) {
    uint4 rn0 = rec[((size_t)s2 << 4) + q];
    float an0 = af[s2];
    uint4 rn1 = rec[((size_t)s3 << 4) + q];
    float an1 = af[s3];
    int s4 = (i + 4 < end) ? srcs[i + 4] : 0;
    int s5 = (i + 5 < end) ? srcs[i + 5] : 0;
    half2v t01a = __builtin_bit_cast(half2v, r0.x);
    half2v t23a = __builtin_bit_cast(half2v, r0.y);
    half2v h01a = __builtin_bit_cast(half2v, r0.z);
    half2v h23a = __builtin_bit_cast(half2v, r0.w);
    half2v t01b = __builtin_bit_cast(half2v, r1.x);
    half2v t23b = __builtin_bit_cast(half2v, r1.y);
    half2v h01b = __builtin_bit_cast(half2v, r1.z);
    half2v h23b = __builtin_bit_cast(half2v, r1.w);
    float p0 = fdot2(t23a, d23, fdot2(t01a, d01, 0.f)) * LOG2E;
    float p1 = fdot2(t23b, d23, fdot2(t01b, d01, 0.f)) * LOG2E;
    rowsum16x2(p0, p1);
    float wf0 = a0 + bfd;
    wf0 = (wf0 > 0.f) ? wf0 : NEG_SLOPE * wf0;
    float wf1 = a1 + bfd;
    wf1 = (wf1 > 0.f) ? wf1 : NEG_SLOPE * wf1;
    if (i + 1 >= end) { p1 = -1e30f; wf1 = -1e30f; }  // tail edge -> exp2 = 0
    float ef0 = fexp2(wf0), ef1 = fexp2(wf1);
    sf += ef0 + ef1;
    zf0 = fmaf((float)h01b[0], ef1, fmaf((float)h01a[0], ef0, zf0));
    zf1 = fmaf((float)h01b[1], ef1, fmaf((float)h01a[1], ef0, zf1));
    zf2 = fmaf((float)h23b[0], ef1, fmaf((float)h23a[0], ef0, zf2));
    zf3 = fmaf((float)h23b[1], ef1, fmaf((float)h23a[1], ef0, zf3));
    float pm0 = p0 - mt;
    if (pm0 > 60.f) {                 // rare: first edge / new-max-by-far
      float sc = fexp2(-pm0);         // ==0 when mt==NEG_BIG
      st *= sc;
      zt0 *= sc; zt1 *= sc; zt2 *= sc; zt3 *= sc;
      mt = p0; pm0 = 0.f;
    }
    float et0 = fexp2(pm0);
    st += et0;
    zt0 = fmaf((float)h01a[0], et0, zt0);
    zt1 = fmaf((float)h01a[1], et0, zt1);
    zt2 = fmaf((float)h23a[0], et0, zt2);
    zt3 = fmaf((float)h23a[1], et0, zt3);
    float pm1 = p1 - mt;
    if (pm1 > 60.f) {
      float sc = fexp2(-pm1);
      st *= sc;
      zt0 *= sc; zt1 *= sc; zt2 *= sc; zt3 *= sc;
      mt = p1; pm1 = 0.f;
    }
    float et1 = fexp2(pm1);
    st += et1;
    zt0 = fmaf((float)h01b[0], et1, zt0);
    zt1 = fmaf((float)h01b[1], et1, zt1);
    zt2 = fmaf((float)h23b[0], et1, zt2);
    zt3 = fmaf((float)h23b[1], et1, zt3);
    r0 = rn0; r1 = rn1; a0 = an0; a1 = an1;
    s2 = s4;  s3 = s5;
  }
  float4 zv = make_float4(0.f, 0.f, 0.f, 0.f);
  if (end > beg) {
    float rf = ETA / sf, rt = (1.f - ETA) / st;
    zv.x = rf * zf0 + rt * zt0;
    zv.y = rf * zf1 + rt * zt1;
    zv.z = rf * zf2 + rt * zt2;
    zv.w = rf * zf3 + rt * zt3;
  }
  uint2 zo;
  zo.x = pack2(zv.x, zv.y);
  zo.y = pack2(zv.z, zv.w);
  ((uint2*)(z + (size_t)d * 64))[q] = zo;
}

// Cooperative mega-kernel: phase0 zero-gcur | phase1 prep+partition |
// phase2 finesort | phase3 fused edge-softmax-aggregate. Grid-stride virtual
// blocks (correct for ANY grid size); grid sized by occupancy on host.
// __launch_bounds__(256,8): 8 blocks/CU target -> VGPR<=64, 32 waves/CU.
__global__ void __launch_bounds__(256, 8)
k_all(const float* __restrict__ h, const float* __restrict__ tax,
      const float* __restrict__ whw,
      const int* __restrict__ src, const int* __restrict__ dst,
      float* __restrict__ af, float* __restrict__ bf, uint4* __restrict__ rec,
      int* __restrict__ gcur, int* __restrict__ pck,
      int* __restrict__ off, int* __restrict__ srcs,
      unsigned short* __restrict__ z,
      int n, int ne, int nb, int npart, int nprep, int bw) {
  cg::grid_group grid = cg::this_grid();
  int nblk = (int)gridDim.x;
  // phase 0: zero bucket cursors
  {
    int t = (int)(blockIdx.x * blockDim.x + threadIdx.x);
    if (t < 512) gcur[t] = 0;
  }
  grid.sync();
  // phase 1: partition (latency-bound, first) + prep (BW-bound) interleaved
  for (int vb = (int)blockIdx.x; vb < npart + nprep; vb += nblk) {
    if (vb < npart) part_body(src, dst, gcur, pck, ne, vb);
    else            prep_body(h, tax, whw, af, bf, rec, n, vb - npart);
  }
  grid.sync();
  // phase 2: finesort. Odd-multiplier permutation spreads the (nb < nblk)
  // buckets across CUs regardless of block->CU packing (pow2 grid).
  {
    int bx = (int)(((unsigned)blockIdx.x * 1031u) & (unsigned)(nblk - 1));
    for (int vb = bx; vb < nb; vb += nblk)
      fine_body(pck, gcur, off, srcs, n, nb, vb);
  }
  grid.sync();
  // phase 3: fused gather/softmax/aggregate
  for (int vb = (int)blockIdx.x; vb < bw; vb += nblk)
    fused_body(rec, af, bf, off, srcs, z, n, vb);
}

// out = z @ W^T + b via MFMA. One wave per 16-node tile, all 64 output cols.
// W split into f16 hi+lo so accuracy stays at f32-weight level.
#ifdef HAVE_MFMA16
__launch_bounds__(256)
__global__ void k_out_gemm(const unsigned short* __restrict__ z,
                           const float* __restrict__ W,
                           const float* __restrict__ b, float* __restrict__ out, int n) {
  int l = threadIdx.x & 63;
  int wv = threadIdx.x >> 6;
  int c16 = l & 15;   // A-row / B-col / D-col within tile
  int seg = l >> 4;   // k-segment selector
  half8v bh[4][2], bl[4][2];
#pragma unroll
  for (int jt = 0; jt < 4; ++jt) {
    const float* wr = W + (size_t)(jt * 16 + c16) * 64 + seg * 8;
#pragma unroll
    for (int ks = 0; ks < 2; ++ks) {
      const float* wk = wr + ks * 32;
#pragma unroll
      for (int e = 0; e < 8; ++e) {
        float wvv = wk[e];
        _Float16 hi = (_Float16)wvv;
        bh[jt][ks][e] = hi;
        bl[jt][ks][e] = (_Float16)(wvv - (float)hi);
      }
    }
  }
  float bias0 = b[c16], bias1 = b[16 + c16], bias2 = b[32 + c16], bias3 = b[48 + c16];
  const half8v* z8 = (const half8v*)z;
  int tiles = (n + 15) >> 4;
  int nw = (int)gridDim.x * 4;
  for (int t = (int)blockIdx.x * 4 + wv; t < tiles; t += nw) {
    int base = t << 4;
    int arow = base + c16;
    size_t zi = (size_t)(arow < n ? arow : n - 1) * 8 + seg;
    half8v a0 = z8[zi];
    half8v a1 = z8[zi + 4];
    f32x4v acc0 = {bias0, bias0, bias0, bias0};
    f32x4v acc1 = {bias1, bias1, bias1, bias1};
    f32x4v acc2 = {bias2, bias2, bias2, bias2};
    f32x4v acc3 = {bias3, bias3, bias3, bias3};
    acc0 = __builtin_amdgcn_mfma_f32_16x16x32_f16(a0, bh[0][0], acc0, 0, 0, 0);
    acc1 = __builtin_amdgcn_mfma_f32_16x16x32_f16(a0, bh[1][0], acc1, 0, 0, 0);
    acc2 = __builtin_amdgcn_mfma_f32_16x16x32_f16(a0, bh[2][0], acc2, 0, 0, 0);
    acc3 = __builtin_amdgcn_mfma_f32_16x16x32_f16(a0, bh[3][0], acc3, 0, 0, 0);
    acc0 = __builtin_amdgcn_mfma_f32_16x16x32_f16(a1, bh[0][1], acc0, 0, 0, 0);
    acc1 = __builtin_amdgcn_mfma_f32_16x16x32_f16(a1, bh[1][1], acc1, 0, 0, 0);
    acc2 = __builtin_amdgcn_mfma_f32_16x16x32_f16(a1, bh[2][1], acc2, 0, 0, 0);
    acc3 = __builtin_amdgcn_mfma_f32_16x16x32_f16(a1, bh[3][1], acc3, 0, 0, 0);
    acc0 = __builtin_amdgcn_mfma_f32_16x16x32_f16(a0, bl[0][0], acc0, 0, 0, 0);
    acc1 = __builtin_amdgcn_mfma_f32_16x16x32_f16(a0, bl[1][0], acc1, 0, 0, 0);
    acc2 = __builtin_amdgcn_mfma_f32_16x16x32_f16(a0, bl[2][0], acc2, 0, 0, 0);
    acc3 = __builtin_amdgcn_mfma_f32_16x16x32_f16(a0, bl[3][0], acc3, 0, 0, 0);
    acc0 = __builtin_amdgcn_mfma_f32_16x16x32_f16(a1, bl[0][1], acc0, 0, 0, 0);
    acc1 = __builtin_amdgcn_mfma_f32_16x16x32_f16(a1, bl[1][1], acc1, 0, 0, 0);
    acc2 = __builtin_amdgcn_mfma_f32_16x16x32_f16(a1, bl[2][1], acc2, 0, 0, 0);
    acc3 = __builtin_amdgcn_mfma_f32_16x16x32_f16(a1, bl[3][1], acc3, 0, 0, 0);
#pragma unroll
    for (int r = 0; r < 4; ++r) {
      int nrow = base + seg * 4 + r;
      if (nrow < n) {
        float* o = out + (size_t)nrow * 64 + c16;
        o[0]  = acc0[r];
        o[16] = acc1[r];
        o[32] = acc2[r];
        o[48] = acc3[r];
      }
    }
  }
}
#else
__launch_bounds__(256)
__global__ void k_out_gemm(const unsigned short* __restrict__ z,
                           const float* __restrict__ W,
                           const float* __restrict__ b, float* __restrict__ out, int n) {
  int t = threadIdx.x;
  int j = t & 63, nl = t >> 6;
  float wreg[64];
#pragma unroll
  for (int i = 0; i < 16; ++i)
    ((float4*)wreg)[i] = ((const float4*)(W + (size_t)j * 64))[i];
  float bias = b[j];
  int stride = gridDim.x * 4;
  for (int node = blockIdx.x * 4 + nl; node < n; node += stride) {
    float zv = (float)__builtin_bit_cast(_Float16, z[(size_t)node * 64 + j]);
    float acc = bias;
#pragma unroll
    for (int k = 0; k < 64; ++k)
      acc += __shfl(zv, k) * wreg[k];
    out[(size_t)node * 64 + j] = acc;
  }
}
#endif

extern "C" void kernel_launch(void* const* d_in, const int* in_sizes, int n_in,
                              void* d_out, int out_size, void* d_ws, size_t ws_size,
                              hipStream_t stream) {
  const float* h   = (const float*)d_in[0];
  const float* tax = (const float*)d_in[1];
  const int*   src = (const int*)d_in[2];
  const int*   dst = (const int*)d_in[3];
  const float* whw = (const float*)d_in[4];
  const float* Ww  = (const float*)d_in[5];
  const float* Wb  = (const float*)d_in[6];
  float* out = (float*)d_out;
  int n  = in_sizes[0] / 64;
  int ne = in_sizes[2];
  int nb = (n + 255) >> 8;  // 256-dst buckets (391 for n=100k); nb<=512

  // Workspace layout (4-byte words; rec aligned to 16 B):
  float* af   = (float*)d_ws;               // n
  float* bf   = af + n;                     // n
  int*   off  = (int*)(bf + n);             // n+2
  int*   srcs = off + n + 2;                // ne
  int*   gcur = srcs + ne;                  // 512
  size_t w = (size_t)(2 * n) + (n + 2) + ne + 512;
  w = (w + 3) & ~(size_t)3;                 // 16B-align
  unsigned short* z = (unsigned short*)((int*)d_ws + w);  // n*64 u16
  uint4* rec = (uint4*)(z + (size_t)n * 64);              // n*16 uint4
  // Packed sort plane aliases z (consumed in phase 2 before z written in 3):
  int* pck = (int*)z;                       // nb*CAP*4B (8.6MB) <= n*128B

  int nprep = (n * 16 + 255) / 256;
  int npart = (ne + PCHUNK - 1) / PCHUNK;
  int bw    = (n + 15) / 16;
  int bg    = (((n + 15) >> 4) + 3) / 4;    // out_gemm: one tile per wave

  // Cooperative grid: max co-resident blocks, rounded down to pow2 (the
  // phase-2 permutation needs pow2). Cached across calls (host query only;
  // graph-capture safe: no allocation, no stream ops).
  static int s_grid = 0;
  if (s_grid == 0) {
    int maxb = 0;
    hipOccupancyMaxActiveBlocksPerMultiprocessor(&maxb, k_all, 256, 0);
    hipDeviceProp_t prop;
    int dev = 0;
    hipGetDevice(&dev);
    hipGetDeviceProperties(&prop, dev);
    long cap = (long)maxb * (long)prop.multiProcessorCount;
    if (cap < 1) cap = 256;
    int g = 1;
    while ((long)(g * 2) <= cap && g < 2048) g *= 2;
    s_grid = g;
  }

  void* args[] = {(void*)&h, (void*)&tax, (void*)&whw, (void*)&src, (void*)&dst,
                  (void*)&af, (void*)&bf, (void*)&rec, (void*)&gcur, (void*)&pck,
                  (void*)&off, (void*)&srcs, (void*)&z,
                  (void*)&n, (void*)&ne, (void*)&nb, (void*)&npart,
                  (void*)&nprep, (void*)&bw};
  hipLaunchCooperativeKernel(k_all, dim3(s_grid), dim3(256), args, 0, stream);
  k_out_gemm<<<bg, 256, 0, stream>>>(z, Ww, Wb, out, n);
}

// Round 6
// 259.027 us; speedup vs baseline: 2.2683x; 2.2683x over previous
//
#include <hip/hip_runtime.h>

#define NEG_SLOPE 0.01f
#define ETA 0.5f
#define NEG_BIG -3.402823466e38f
#define LOG2E 1.4426950408889634f
#define PCHUNK 4096   // edges per partition block
#define CAP 5504      // per-bucket capacity (mean 4096 + 22 sigma)

typedef _Float16 half2v __attribute__((ext_vector_type(2)));
typedef _Float16 half8v __attribute__((ext_vector_type(8)));
typedef float f32x4v __attribute__((ext_vector_type(4)));

#if defined(__has_builtin)
#if __has_builtin(__builtin_amdgcn_fdot2)
#define HAVE_FDOT2 1
#endif
#if __has_builtin(__builtin_amdgcn_exp2f)
#define HAVE_EXP2 1
#endif
#if __has_builtin(__builtin_amdgcn_update_dpp)
#define HAVE_DPP 1
#endif
#if __has_builtin(__builtin_amdgcn_mfma_f32_16x16x32_f16)
#define HAVE_MFMA16 1
#endif
#endif

__device__ __forceinline__ float fdot2(half2v a, half2v b, float c) {
#ifdef HAVE_FDOT2
  return __builtin_amdgcn_fdot2(a, b, c, false);
#else
  return (float)a[0] * (float)b[0] + (float)a[1] * (float)b[1] + c;
#endif
}

__device__ __forceinline__ unsigned pack2(float x, float y) {
  half2v h = {( _Float16)x, (_Float16)y};
  return __builtin_bit_cast(unsigned, h);
}

__device__ __forceinline__ float fexp2(float x) {
#ifdef HAVE_EXP2
  return __builtin_amdgcn_exp2f(x);
#else
  return __expf(x * 0.6931471805599453f);
#endif
}

// Interleaved dual 16-lane row-sum (VALU pipe, no LDS).
__device__ __forceinline__ void rowsum16x2(float& x, float& y) {
#ifdef HAVE_DPP
#define DPPADD(v, ctl)                                                        \
  v += __builtin_bit_cast(float, __builtin_amdgcn_update_dpp(                 \
         0, __builtin_bit_cast(int, v), ctl, 0xf, 0xf, true))
  DPPADD(x, 0x121); DPPADD(y, 0x121);   // row_ror:1
  DPPADD(x, 0x122); DPPADD(y, 0x122);   // row_ror:2
  DPPADD(x, 0x124); DPPADD(y, 0x124);   // row_ror:4
  DPPADD(x, 0x128); DPPADD(y, 0x128);   // row_ror:8
#undef DPPADD
#else
#pragma unroll
  for (int o = 1; o < 16; o <<= 1) {
    x += __shfl_xor(x, o);
    y += __shfl_xor(y, o);
  }
#endif
}

// ---- prep: node dots af/bf (pre-scaled by log2e) + interleaved f16 record ----
__device__ __forceinline__ void prep_body(const float* __restrict__ h,
                                          const float* __restrict__ tax,
                                          const float* __restrict__ whw,
                                          float* __restrict__ af, float* __restrict__ bf,
                                          uint4* __restrict__ rec, int n, int blk) {
  int gid = blk * 256 + (int)threadIdx.x;
  int node = gid >> 4, lane = gid & 15;
  if (node >= n) return;
  float4 x  = ((const float4*)(h + (size_t)node * 64))[lane];
  float4 tx = ((const float4*)(tax + (size_t)node * 64))[lane];
  float4 wa = ((const float4*)whw)[lane];
  float4 wb = ((const float4*)(whw + 64))[lane];
  uint4 r;
  r.x = pack2(tx.x, tx.y);
  r.y = pack2(tx.z, tx.w);
  r.z = pack2(x.x, x.y);
  r.w = pack2(x.z, x.w);
  rec[((size_t)node << 4) + lane] = r;
  float pa = x.x * wa.x + x.y * wa.y + x.z * wa.z + x.w * wa.w;
  float pb = x.x * wb.x + x.y * wb.y + x.z * wb.z + x.w * wb.w;
#pragma unroll
  for (int o = 8; o; o >>= 1) {
    pa += __shfl_xor(pa, o);
    pb += __shfl_xor(pb, o);
  }
  // leaky_relu(c*x) == c*leaky_relu(x) for c>0: exp2-domain prescale is exact.
  if (lane == 0) { af[node] = pa * LOG2E; bf[node] = pb * LOG2E; }
}

// ---- partition by bucket = dst>>8 (391 buckets of 256 dsts) ----
__device__ __forceinline__ void part_body(const int* __restrict__ src,
                                          const int* __restrict__ dst,
                                          int* __restrict__ gcur, int* __restrict__ pck,
                                          int ne, int blk) {
  __shared__ int s_hist[512];
  __shared__ int s_res[512];
  __shared__ int s_cur[512];
  int t = threadIdx.x;
  int base = blk * PCHUNK;
  int cnt = ne - base; if (cnt > PCHUNK) cnt = PCHUNK;
  s_hist[t] = 0; s_hist[t + 256] = 0;
  __syncthreads();
  int i = t * 4;
  for (; i + 3 < cnt; i += 1024) {
    int4 dd = *(const int4*)(dst + base + i);
    atomicAdd(&s_hist[dd.x >> 8], 1);
    atomicAdd(&s_hist[dd.y >> 8], 1);
    atomicAdd(&s_hist[dd.z >> 8], 1);
    atomicAdd(&s_hist[dd.w >> 8], 1);
  }
  for (; i < cnt; ++i) atomicAdd(&s_hist[dst[base + i] >> 8], 1);
  __syncthreads();
  int v0 = s_hist[t], v1 = s_hist[t + 256];
  if (v0 > 0) s_res[t] = atomicAdd(&gcur[t], v0);
  if (v1 > 0) s_res[t + 256] = atomicAdd(&gcur[t + 256], v1);
  s_cur[t] = 0; s_cur[t + 256] = 0;
  __syncthreads();
  i = t * 4;
  for (; i + 3 < cnt; i += 1024) {
    int4 dd = *(const int4*)(dst + base + i);
    int4 ss = *(const int4*)(src + base + i);
    int r, g;
    r = dd.x >> 8; g = s_res[r] + atomicAdd(&s_cur[r], 1);
    if (g < CAP) pck[(size_t)r * CAP + g] = (ss.x << 8) | (dd.x & 255);
    r = dd.y >> 8; g = s_res[r] + atomicAdd(&s_cur[r], 1);
    if (g < CAP) pck[(size_t)r * CAP + g] = (ss.y << 8) | (dd.y & 255);
    r = dd.z >> 8; g = s_res[r] + atomicAdd(&s_cur[r], 1);
    if (g < CAP) pck[(size_t)r * CAP + g] = (ss.z << 8) | (dd.z & 255);
    r = dd.w >> 8; g = s_res[r] + atomicAdd(&s_cur[r], 1);
    if (g < CAP) pck[(size_t)r * CAP + g] = (ss.w << 8) | (dd.w & 255);
  }
  for (; i < cnt; ++i) {
    int d = dst[base + i];
    int r = d >> 8;
    int g = s_res[r] + atomicAdd(&s_cur[r], 1);
    if (g < CAP) pck[(size_t)r * CAP + g] = (src[base + i] << 8) | (d & 255);
  }
}

// Fused prep + partition. Partition blocks FIRST (latency-bound) so they
// overlap prep's BW-bound streaming. gcur zeroed by memset.
__global__ void k_prep_part(const float* __restrict__ h, const float* __restrict__ tax,
                            const float* __restrict__ whw,
                            float* __restrict__ af, float* __restrict__ bf,
                            uint4* __restrict__ rec,
                            const int* __restrict__ src, const int* __restrict__ dst,
                            int* __restrict__ gcur, int* __restrict__ pck,
                            int n, int ne, int npart) {
  int b = (int)blockIdx.x;
  if (b < npart) part_body(src, dst, gcur, pck, ne, b);
  else           prep_body(h, tax, whw, af, bf, rec, n, b - npart);
}

// One block per 256-dst bucket: exact CSR via LDS hist + 256-wide scan.
__global__ void k_finesort(const int* __restrict__ pck, const int* __restrict__ gcur,
                           int* __restrict__ off, int* __restrict__ srcs,
                           int n, int nb) {
  __shared__ int s_hist[256];
  __shared__ int s_scan[256];
  __shared__ int s_cur[256];
  __shared__ int s_red[256];
  int b = blockIdx.x;
  int t = threadIdx.x;
  int cnt = gcur[b];
  size_t gbase = (size_t)b * CAP;
  int r0 = (t < b) ? gcur[t] : 0;
  int r1 = (t + 256 < b) ? gcur[t + 256] : 0;
  s_red[t] = r0 + r1;
  s_hist[t] = 0;
  __syncthreads();
  for (int s = 128; s; s >>= 1) {
    if (t < s) s_red[t] += s_red[t + s];
    __syncthreads();
  }
  int base = s_red[0];
  int i = t;
  for (; i + 768 < cnt; i += 1024) {
    int p0 = pck[gbase + i];
    int p1 = pck[gbase + i + 256];
    int p2 = pck[gbase + i + 512];
    int p3 = pck[gbase + i + 768];
    atomicAdd(&s_hist[p0 & 255], 1);
    atomicAdd(&s_hist[p1 & 255], 1);
    atomicAdd(&s_hist[p2 & 255], 1);
    atomicAdd(&s_hist[p3 & 255], 1);
  }
  for (; i < cnt; i += 256) atomicAdd(&s_hist[pck[gbase + i] & 255], 1);
  __syncthreads();
  int v = s_hist[t];
  s_scan[t] = v;
  __syncthreads();
  for (int s = 1; s < 256; s <<= 1) {
    int a = (t >= s) ? s_scan[t - s] : 0;
    __syncthreads();
    s_scan[t] += a;
    __syncthreads();
  }
  int pex = s_scan[t] - v;
  int d0 = (b << 8) + t;
  if (d0 < n) off[d0] = base + pex;
  if (b == nb - 1 && t == 0) off[n] = base + cnt;
  s_cur[t] = pex;
  __syncthreads();
  i = t;
  for (; i + 768 < cnt; i += 1024) {
    int p0 = pck[gbase + i];
    int p1 = pck[gbase + i + 256];
    int p2 = pck[gbase + i + 512];
    int p3 = pck[gbase + i + 768];
    int k0 = atomicAdd(&s_cur[p0 & 255], 1);
    srcs[base + k0] = p0 >> 8;
    int k1 = atomicAdd(&s_cur[p1 & 255], 1);
    srcs[base + k1] = p1 >> 8;
    int k2 = atomicAdd(&s_cur[p2 & 255], 1);
    srcs[base + k2] = p2 >> 8;
    int k3 = atomicAdd(&s_cur[p3 & 255], 1);
    srcs[base + k3] = p3 >> 8;
  }
  for (; i < cnt; i += 256) {
    int p = pck[gbase + i];
    int k = atomicAdd(&s_cur[p & 255], 1);
    srcs[base + k] = p >> 8;
  }
}

// One 16-lane group per dst node (4 nodes/wave), pair-unrolled 4-stage
// software pipeline, THREE pairs in flight: srcs read 3 pairs ahead,
// rec/af issued 2 pairs ahead, compute on current pair. Steady-state
// 12 rec-gathers in flight per wave (1.5x r2's version). All pipeline
// state in named scalars (no runtime-indexed arrays -> no scratch).
__launch_bounds__(256)
__global__ void k_fused(const uint4* __restrict__ rec,
                        const float* __restrict__ af, const float* __restrict__ bf,
                        const int* __restrict__ off, const int* __restrict__ srcs,
                        unsigned short* __restrict__ z, int n) {
  int d = (int)((blockIdx.x * blockDim.x + threadIdx.x) >> 4);
  int q = threadIdx.x & 15;
  if (d >= n) return;
  // dst side needs only its tax half: 8B instead of 16B.
  uint2 rd = *(const uint2*)((const char*)rec + ((((size_t)d << 4) + q) << 4));
  half2v d01 = __builtin_bit_cast(half2v, rd.x);
  half2v d23 = __builtin_bit_cast(half2v, rd.y);
  float bfd = bf[d];
  int beg = off[d], end = off[d + 1];
  float sf = 0.f, st = 0.f, mt = NEG_BIG;
  float zf0 = 0.f, zf1 = 0.f, zf2 = 0.f, zf3 = 0.f;
  float zt0 = 0.f, zt1 = 0.f, zt2 = 0.f, zt3 = 0.f;
  // ---- pipeline prologue: pairs 0 and 1 gathered, pair 2 addresses ready ----
  int s0 = (beg     < end) ? srcs[beg]     : 0;
  int s1 = (beg + 1 < end) ? srcs[beg + 1] : 0;
  int s2 = (beg + 2 < end) ? srcs[beg + 2] : 0;
  int s3 = (beg + 3 < end) ? srcs[beg + 3] : 0;
  uint4 rA = rec[((size_t)s0 << 4) + q];
  float aA = af[s0];
  uint4 rB = rec[((size_t)s1 << 4) + q];
  float aB = af[s1];
  uint4 rC = rec[((size_t)s2 << 4) + q];
  float aC = af[s2];
  uint4 rD = rec[((size_t)s3 << 4) + q];
  float aD = af[s3];
  int s4 = (beg + 4 < end) ? srcs[beg + 4] : 0;
  int s5 = (beg + 5 < end) ? srcs[beg + 5] : 0;
  for (int i = beg; i < end; i += 2) {
    // stage B: issue pair+2's gathers (addresses ready from last iter)
    uint4 rE = rec[((size_t)s4 << 4) + q];
    float aE = af[s4];
    uint4 rF = rec[((size_t)s5 << 4) + q];
    float aF = af[s5];
    // stage A: read srcs three pairs ahead (sequential, cache-hot)
    int s6 = (i + 6 < end) ? srcs[i + 6] : 0;
    int s7 = (i + 7 < end) ? srcs[i + 7] : 0;
    // stage C: compute current pair (rA/aA = edge i, rB/aB = edge i+1)
    half2v t01a = __builtin_bit_cast(half2v, rA.x);
    half2v t23a = __builtin_bit_cast(half2v, rA.y);
    half2v h01a = __builtin_bit_cast(half2v, rA.z);
    half2v h23a = __builtin_bit_cast(half2v, rA.w);
    half2v t01b = __builtin_bit_cast(half2v, rB.x);
    half2v t23b = __builtin_bit_cast(half2v, rB.y);
    half2v h01b = __builtin_bit_cast(half2v, rB.z);
    half2v h23b = __builtin_bit_cast(half2v, rB.w);
    float p0 = fdot2(t23a, d23, fdot2(t01a, d01, 0.f)) * LOG2E;
    float p1 = fdot2(t23b, d23, fdot2(t01b, d01, 0.f)) * LOG2E;
    rowsum16x2(p0, p1);
    float wf0 = aA + bfd;
    wf0 = (wf0 > 0.f) ? wf0 : NEG_SLOPE * wf0;
    float wf1 = aB + bfd;
    wf1 = (wf1 > 0.f) ? wf1 : NEG_SLOPE * wf1;
    if (i + 1 >= end) { p1 = -1e30f; wf1 = -1e30f; }  // tail edge -> exp2 = 0
    float ef0 = fexp2(wf0), ef1 = fexp2(wf1);
    sf += ef0 + ef1;
    zf0 = fmaf((float)h01b[0], ef1, fmaf((float)h01a[0], ef0, zf0));
    zf1 = fmaf((float)h01b[1], ef1, fmaf((float)h01a[1], ef0, zf1));
    zf2 = fmaf((float)h23b[0], ef1, fmaf((float)h23a[0], ef0, zf2));
    zf3 = fmaf((float)h23b[1], ef1, fmaf((float)h23a[1], ef0, zf3));
    float pm0 = p0 - mt;
    if (pm0 > 60.f) {                 // rare: first edge / new-max-by-far
      float sc = fexp2(-pm0);         // ==0 when mt==NEG_BIG
      st *= sc;
      zt0 *= sc; zt1 *= sc; zt2 *= sc; zt3 *= sc;
      mt = p0; pm0 = 0.f;
    }
    float et0 = fexp2(pm0);
    st += et0;
    zt0 = fmaf((float)h01a[0], et0, zt0);
    zt1 = fmaf((float)h01a[1], et0, zt1);
    zt2 = fmaf((float)h23a[0], et0, zt2);
    zt3 = fmaf((float)h23a[1], et0, zt3);
    float pm1 = p1 - mt;
    if (pm1 > 60.f) {
      float sc = fexp2(-pm1);
      st *= sc;
      zt0 *= sc; zt1 *= sc; zt2 *= sc; zt3 *= sc;
      mt = p1; pm1 = 0.f;
    }
    float et1 = fexp2(pm1);
    st += et1;
    zt0 = fmaf((float)h01b[0], et1, zt0);
    zt1 = fmaf((float)h01b[1], et1, zt1);
    zt2 = fmaf((float)h23b[0], et1, zt2);
    zt3 = fmaf((float)h23b[1], et1, zt3);
    // rotate pipeline (named scalars only)
    rA = rC; aA = aC; rB = rD; aB = aD;
    rC = rE; aC = aE; rD = rF; aD = aF;
    s4 = s6; s5 = s7;
  }
  float4 zv = make_float4(0.f, 0.f, 0.f, 0.f);
  if (end > beg) {
    float rf = ETA / sf, rt = (1.f - ETA) / st;
    zv.x = rf * zf0 + rt * zt0;
    zv.y = rf * zf1 + rt * zt1;
    zv.z = rf * zf2 + rt * zt2;
    zv.w = rf * zf3 + rt * zt3;
  }
  uint2 zo;
  zo.x = pack2(zv.x, zv.y);
  zo.y = pack2(zv.z, zv.w);
  ((uint2*)(z + (size_t)d * 64))[q] = zo;
}

// out = z @ W^T + b via MFMA. One wave per 16-node tile, all 64 output cols.
// W split into f16 hi+lo so accuracy stays at f32-weight level.
#ifdef HAVE_MFMA16
__launch_bounds__(256)
__global__ void k_out_gemm(const unsigned short* __restrict__ z,
                           const float* __restrict__ W,
                           const float* __restrict__ b, float* __restrict__ out, int n) {
  int l = threadIdx.x & 63;
  int wv = threadIdx.x >> 6;
  int c16 = l & 15;   // A-row / B-col / D-col within tile
  int seg = l >> 4;   // k-segment selector
  half8v bh[4][2], bl[4][2];
#pragma unroll
  for (int jt = 0; jt < 4; ++jt) {
    const float* wr = W + (size_t)(jt * 16 + c16) * 64 + seg * 8;
#pragma unroll
    for (int ks = 0; ks < 2; ++ks) {
      const float* wk = wr + ks * 32;
#pragma unroll
      for (int e = 0; e < 8; ++e) {
        float wvv = wk[e];
        _Float16 hi = (_Float16)wvv;
        bh[jt][ks][e] = hi;
        bl[jt][ks][e] = (_Float16)(wvv - (float)hi);
      }
    }
  }
  float bias0 = b[c16], bias1 = b[16 + c16], bias2 = b[32 + c16], bias3 = b[48 + c16];
  const half8v* z8 = (const half8v*)z;
  int tiles = (n + 15) >> 4;
  int nw = (int)gridDim.x * 4;
  for (int t = (int)blockIdx.x * 4 + wv; t < tiles; t += nw) {
    int base = t << 4;
    int arow = base + c16;
    size_t zi = (size_t)(arow < n ? arow : n - 1) * 8 + seg;
    half8v a0 = z8[zi];
    half8v a1 = z8[zi + 4];
    f32x4v acc0 = {bias0, bias0, bias0, bias0};
    f32x4v acc1 = {bias1, bias1, bias1, bias1};
    f32x4v acc2 = {bias2, bias2, bias2, bias2};
    f32x4v acc3 = {bias3, bias3, bias3, bias3};
    acc0 = __builtin_amdgcn_mfma_f32_16x16x32_f16(a0, bh[0][0], acc0, 0, 0, 0);
    acc1 = __builtin_amdgcn_mfma_f32_16x16x32_f16(a0, bh[1][0], acc1, 0, 0, 0);
    acc2 = __builtin_amdgcn_mfma_f32_16x16x32_f16(a0, bh[2][0], acc2, 0, 0, 0);
    acc3 = __builtin_amdgcn_mfma_f32_16x16x32_f16(a0, bh[3][0], acc3, 0, 0, 0);
    acc0 = __builtin_amdgcn_mfma_f32_16x16x32_f16(a1, bh[0][1], acc0, 0, 0, 0);
    acc1 = __builtin_amdgcn_mfma_f32_16x16x32_f16(a1, bh[1][1], acc1, 0, 0, 0);
    acc2 = __builtin_amdgcn_mfma_f32_16x16x32_f16(a1, bh[2][1], acc2, 0, 0, 0);
    acc3 = __builtin_amdgcn_mfma_f32_16x16x32_f16(a1, bh[3][1], acc3, 0, 0, 0);
    acc0 = __builtin_amdgcn_mfma_f32_16x16x32_f16(a0, bl[0][0], acc0, 0, 0, 0);
    acc1 = __builtin_amdgcn_mfma_f32_16x16x32_f16(a0, bl[1][0], acc1, 0, 0, 0);
    acc2 = __builtin_amdgcn_mfma_f32_16x16x32_f16(a0, bl[2][0], acc2, 0, 0, 0);
    acc3 = __builtin_amdgcn_mfma_f32_16x16x32_f16(a0, bl[3][0], acc3, 0, 0, 0);
    acc0 = __builtin_amdgcn_mfma_f32_16x16x32_f16(a1, bl[0][1], acc0, 0, 0, 0);
    acc1 = __builtin_amdgcn_mfma_f32_16x16x32_f16(a1, bl[1][1], acc1, 0, 0, 0);
    acc2 = __builtin_amdgcn_mfma_f32_16x16x32_f16(a1, bl[2][1], acc2, 0, 0, 0);
    acc3 = __builtin_amdgcn_mfma_f32_16x16x32_f16(a1, bl[3][1], acc3, 0, 0, 0);
#pragma unroll
    for (int r = 0; r < 4; ++r) {
      int nrow = base + seg * 4 + r;
      if (nrow < n) {
        float* o = out + (size_t)nrow * 64 + c16;
        o[0]  = acc0[r];
        o[16] = acc1[r];
        o[32] = acc2[r];
        o[48] = acc3[r];
      }
    }
  }
}
#else
__launch_bounds__(256)
__global__ void k_out_gemm(const unsigned short* __restrict__ z,
                           const float* __restrict__ W,
                           const float* __restrict__ b, float* __restrict__ out, int n) {
  int t = threadIdx.x;
  int j = t & 63, nl = t >> 6;
  float wreg[64];
#pragma unroll
  for (int i = 0; i < 16; ++i)
    ((float4*)wreg)[i] = ((const float4*)(W + (size_t)j * 64))[i];
  float bias = b[j];
  int stride = gridDim.x * 4;
  for (int node = blockIdx.x * 4 + nl; node < n; node += stride) {
    float zv = (float)__builtin_bit_cast(_Float16, z[(size_t)node * 64 + j]);
    float acc = bias;
#pragma unroll
    for (int k = 0; k < 64; ++k)
      acc += __shfl(zv, k) * wreg[k];
    out[(size_t)node * 64 + j] = acc;
  }
}
#endif

extern "C" void kernel_launch(void* const* d_in, const int* in_sizes, int n_in,
                              void* d_out, int out_size, void* d_ws, size_t ws_size,
                              hipStream_t stream) {
  const float* h   = (const float*)d_in[0];
  const float* tax = (const float*)d_in[1];
  const int*   src = (const int*)d_in[2];
  const int*   dst = (const int*)d_in[3];
  const float* whw = (const float*)d_in[4];
  const float* Ww  = (const float*)d_in[5];
  const float* Wb  = (const float*)d_in[6];
  float* out = (float*)d_out;
  int n  = in_sizes[0] / 64;
  int ne = in_sizes[2];
  int nb = (n + 255) >> 8;  // 256-dst buckets (391 for n=100k); nb<=512

  // Workspace layout (4-byte words; rec aligned to 16 B):
  float* af   = (float*)d_ws;               // n
  float* bf   = af + n;                     // n
  int*   off  = (int*)(bf + n);             // n+2
  int*   srcs = off + n + 2;                // ne
  int*   gcur = srcs + ne;                  // 512
  size_t w = (size_t)(2 * n) + (n + 2) + ne + 512;
  w = (w + 3) & ~(size_t)3;                 // 16B-align
  unsigned short* z = (unsigned short*)((int*)d_ws + w);  // n*64 u16
  uint4* rec = (uint4*)(z + (size_t)n * 64);              // n*16 uint4
  // Packed sort plane aliases z (consumed by k_finesort before z written):
  int* pck = (int*)z;                       // nb*CAP*4B (8.6MB) <= n*128B

  int nprep = (n * 16 + 255) / 256;
  int npart = (ne + PCHUNK - 1) / PCHUNK;
  int bw    = (n + 15) / 16;
  int bg    = (((n + 15) >> 4) + 3) / 4;    // out_gemm: one tile per wave

  hipMemsetAsync(gcur, 0, 512 * sizeof(int), stream);
  k_prep_part<<<npart + nprep, 256, 0, stream>>>(h, tax, whw, af, bf, rec,
                                                 src, dst, gcur, pck, n, ne, npart);
  k_finesort<<<nb, 256, 0, stream>>>(pck, gcur, off, srcs, n, nb);
  k_fused<<<bw, 256, 0, stream>>>(rec, af, bf, off, srcs, z, n);
  k_out_gemm<<<bg, 256, 0, stream>>>(z, Ww, Wb, out, n);
}

// Round 7
// 227.493 us; speedup vs baseline: 2.5828x; 1.1386x over previous
//
#include <hip/hip_runtime.h>

#define NEG_SLOPE 0.01f
#define ETA 0.5f
#define NEG_BIG -3.402823466e38f
#define LOG2E 1.4426950408889634f
#define PCHUNK 4096   // edges per partition block
#define CAP 1536      // per-64-dst-bucket capacity (mean 1024 + 16 sigma)
#define NBMAX 1568    // max buckets supported by partition LDS (n <= 100352)

typedef _Float16 half2v __attribute__((ext_vector_type(2)));
typedef _Float16 half8v __attribute__((ext_vector_type(8)));
typedef float f32x4v __attribute__((ext_vector_type(4)));

#if defined(__has_builtin)
#if __has_builtin(__builtin_amdgcn_fdot2)
#define HAVE_FDOT2 1
#endif
#if __has_builtin(__builtin_amdgcn_exp2f)
#define HAVE_EXP2 1
#endif
#if __has_builtin(__builtin_amdgcn_update_dpp)
#define HAVE_DPP 1
#endif
#if __has_builtin(__builtin_amdgcn_mfma_f32_16x16x32_f16)
#define HAVE_MFMA16 1
#endif
#endif

__device__ __forceinline__ float fdot2(half2v a, half2v b, float c) {
#ifdef HAVE_FDOT2
  return __builtin_amdgcn_fdot2(a, b, c, false);
#else
  return (float)a[0] * (float)b[0] + (float)a[1] * (float)b[1] + c;
#endif
}

__device__ __forceinline__ unsigned pack2(float x, float y) {
  half2v h = {( _Float16)x, (_Float16)y};
  return __builtin_bit_cast(unsigned, h);
}

__device__ __forceinline__ float fexp2(float x) {
#ifdef HAVE_EXP2
  return __builtin_amdgcn_exp2f(x);
#else
  return __expf(x * 0.6931471805599453f);
#endif
}

// Interleaved dual 16-lane row-sum (VALU pipe, no LDS).
__device__ __forceinline__ void rowsum16x2(float& x, float& y) {
#ifdef HAVE_DPP
#define DPPADD(v, ctl)                                                        \
  v += __builtin_bit_cast(float, __builtin_amdgcn_update_dpp(                 \
         0, __builtin_bit_cast(int, v), ctl, 0xf, 0xf, true))
  DPPADD(x, 0x121); DPPADD(y, 0x121);   // row_ror:1
  DPPADD(x, 0x122); DPPADD(y, 0x122);   // row_ror:2
  DPPADD(x, 0x124); DPPADD(y, 0x124);   // row_ror:4
  DPPADD(x, 0x128); DPPADD(y, 0x128);   // row_ror:8
#undef DPPADD
#else
#pragma unroll
  for (int o = 1; o < 16; o <<= 1) {
    x += __shfl_xor(x, o);
    y += __shfl_xor(y, o);
  }
#endif
}

// ---- prep: node dots af/bf (pre-scaled by log2e) + interleaved f16 record ----
__device__ __forceinline__ void prep_body(const float* __restrict__ h,
                                          const float* __restrict__ tax,
                                          const float* __restrict__ whw,
                                          float* __restrict__ af, float* __restrict__ bf,
                                          uint4* __restrict__ rec, int n, int blk) {
  int gid = blk * 256 + (int)threadIdx.x;
  int node = gid >> 4, lane = gid & 15;
  if (node >= n) return;
  float4 x  = ((const float4*)(h + (size_t)node * 64))[lane];
  float4 tx = ((const float4*)(tax + (size_t)node * 64))[lane];
  float4 wa = ((const float4*)whw)[lane];
  float4 wb = ((const float4*)(whw + 64))[lane];
  uint4 r;
  r.x = pack2(tx.x, tx.y);
  r.y = pack2(tx.z, tx.w);
  r.z = pack2(x.x, x.y);
  r.w = pack2(x.z, x.w);
  rec[((size_t)node << 4) + lane] = r;
  float pa = x.x * wa.x + x.y * wa.y + x.z * wa.z + x.w * wa.w;
  float pb = x.x * wb.x + x.y * wb.y + x.z * wb.z + x.w * wb.w;
#pragma unroll
  for (int o = 8; o; o >>= 1) {
    pa += __shfl_xor(pa, o);
    pb += __shfl_xor(pb, o);
  }
  // leaky_relu(c*x) == c*leaky_relu(x) for c>0: exp2-domain prescale is exact.
  if (lane == 0) { af[node] = pa * LOG2E; bf[node] = pb * LOG2E; }
}

// ---- partition by bucket = dst>>6 (64-dst buckets) ----
// Single LDS array: histogram -> global reservation (stored in place) ->
// cursor for the scatter. Packed word: (src<<6)|(dst&63).
__device__ __forceinline__ void part_body(const int* __restrict__ src,
                                          const int* __restrict__ dst,
                                          int* __restrict__ gcur, int* __restrict__ pck,
                                          int ne, int nb, int blk) {
  __shared__ int s_hist[NBMAX];
  int t = threadIdx.x;
  int base = blk * PCHUNK;
  int cnt = ne - base; if (cnt > PCHUNK) cnt = PCHUNK;
  for (int j = t; j < nb; j += 256) s_hist[j] = 0;
  __syncthreads();
  int i = t * 4;
  for (; i + 3 < cnt; i += 1024) {
    int4 dd = *(const int4*)(dst + base + i);
    atomicAdd(&s_hist[dd.x >> 6], 1);
    atomicAdd(&s_hist[dd.y >> 6], 1);
    atomicAdd(&s_hist[dd.z >> 6], 1);
    atomicAdd(&s_hist[dd.w >> 6], 1);
  }
  for (; i < cnt; ++i) atomicAdd(&s_hist[dst[base + i] >> 6], 1);
  __syncthreads();
  for (int j = t; j < nb; j += 256) {
    int v = s_hist[j];
    if (v > 0) s_hist[j] = atomicAdd(&gcur[j], v);  // global base -> cursor
  }
  __syncthreads();
  i = t * 4;
  for (; i + 3 < cnt; i += 1024) {
    int4 dd = *(const int4*)(dst + base + i);
    int4 ss = *(const int4*)(src + base + i);
    int r, g;
    r = dd.x >> 6; g = atomicAdd(&s_hist[r], 1);
    if (g < CAP) pck[(size_t)r * CAP + g] = (ss.x << 6) | (dd.x & 63);
    r = dd.y >> 6; g = atomicAdd(&s_hist[r], 1);
    if (g < CAP) pck[(size_t)r * CAP + g] = (ss.y << 6) | (dd.y & 63);
    r = dd.z >> 6; g = atomicAdd(&s_hist[r], 1);
    if (g < CAP) pck[(size_t)r * CAP + g] = (ss.z << 6) | (dd.z & 63);
    r = dd.w >> 6; g = atomicAdd(&s_hist[r], 1);
    if (g < CAP) pck[(size_t)r * CAP + g] = (ss.w << 6) | (dd.w & 63);
  }
  for (; i < cnt; ++i) {
    int d = dst[base + i];
    int r = d >> 6;
    int g = atomicAdd(&s_hist[r], 1);
    if (g < CAP) pck[(size_t)r * CAP + g] = (src[base + i] << 6) | (d & 63);
  }
}

// Fused prep + partition. Partition blocks FIRST (latency-bound) so they
// overlap prep's BW-bound streaming. gcur zeroed by memset.
__global__ void k_prep_part(const float* __restrict__ h, const float* __restrict__ tax,
                            const float* __restrict__ whw,
                            float* __restrict__ af, float* __restrict__ bf,
                            uint4* __restrict__ rec,
                            const int* __restrict__ src, const int* __restrict__ dst,
                            int* __restrict__ gcur, int* __restrict__ pck,
                            int n, int ne, int nb, int npart) {
  int b = (int)blockIdx.x;
  if (b < npart) part_body(src, dst, gcur, pck, ne, nb, b);
  else           prep_body(h, tax, whw, af, bf, rec, n, b - npart);
}

// MERGED finesort + gather: one block per 64-dst bucket (nb=1563 blocks,
// ~7KB LDS -> 8 blocks/CU, 32 waves/CU). In-block: 64-bin hist from pck
// (coalesced), wave-0 shuffle scan, LDS scatter to s_srcs; then the proven
// 2-deep-pipelined gather (16 groups x 4 dst-rounds), srcs read from LDS.
// No global off/srcs arrays, no global base reduce.
__launch_bounds__(256)
__global__ void k_fused(const uint4* __restrict__ rec,
                        const float* __restrict__ af, const float* __restrict__ bf,
                        const int* __restrict__ gcur, const int* __restrict__ pck,
                        unsigned short* __restrict__ z, int n) {
  __shared__ int s_hist[64];
  __shared__ int s_off[65];
  __shared__ int s_cur[64];
  __shared__ int s_srcs[CAP];
  int b = (int)blockIdx.x;
  int t = (int)threadIdx.x;
  int cnt = gcur[b]; if (cnt > CAP) cnt = CAP;
  const int* pb = pck + (size_t)b * CAP;
  if (t < 64) s_hist[t] = 0;
  __syncthreads();
  for (int i = t; i < cnt; i += 256) atomicAdd(&s_hist[pb[i] & 63], 1);
  __syncthreads();
  if (t < 64) {
    int x = s_hist[t];
#pragma unroll
    for (int o = 1; o < 64; o <<= 1) {   // wave-0 inclusive scan
      int y = __shfl_up(x, o);
      if (t >= o) x += y;
    }
    s_off[t + 1] = x;
    if (t == 0) s_off[0] = 0;
  }
  __syncthreads();
  if (t < 64) s_cur[t] = s_off[t];
  __syncthreads();
  for (int i = t; i < cnt; i += 256) {
    int p = pb[i];
    int r = atomicAdd(&s_cur[p & 63], 1);
    s_srcs[r] = p >> 6;
  }
  __syncthreads();
  // ---- gather phase: group g handles local dsts g, g+16, g+32, g+48 ----
  int g = t >> 4, q = t & 15;
#pragma unroll
  for (int rnd = 0; rnd < 4; ++rnd) {
    int ld = g + (rnd << 4);
    int d = (b << 6) + ld;
    if (d >= n) continue;
    uint2 rd = *(const uint2*)((const char*)rec + ((((size_t)d << 4) + q) << 4));
    half2v d01 = __builtin_bit_cast(half2v, rd.x);
    half2v d23 = __builtin_bit_cast(half2v, rd.y);
    float bfd = bf[d];
    int beg = s_off[ld], end = s_off[ld + 1];
    float sf = 0.f, st = 0.f, mt = NEG_BIG;
    float zf0 = 0.f, zf1 = 0.f, zf2 = 0.f, zf3 = 0.f;
    float zt0 = 0.f, zt1 = 0.f, zt2 = 0.f, zt3 = 0.f;
    int s0 = (beg     < end) ? s_srcs[beg]     : 0;
    int s1 = (beg + 1 < end) ? s_srcs[beg + 1] : 0;
    uint4 r0 = rec[((size_t)s0 << 4) + q];
    float a0 = af[s0];
    uint4 r1 = rec[((size_t)s1 << 4) + q];
    float a1 = af[s1];
    int s2 = (beg + 2 < end) ? s_srcs[beg + 2] : 0;
    int s3 = (beg + 3 < end) ? s_srcs[beg + 3] : 0;
    for (int i = beg; i < end; i += 2) {
      uint4 rn0 = rec[((size_t)s2 << 4) + q];
      float an0 = af[s2];
      uint4 rn1 = rec[((size_t)s3 << 4) + q];
      float an1 = af[s3];
      int s4 = (i + 4 < end) ? s_srcs[i + 4] : 0;
      int s5 = (i + 5 < end) ? s_srcs[i + 5] : 0;
      half2v t01a = __builtin_bit_cast(half2v, r0.x);
      half2v t23a = __builtin_bit_cast(half2v, r0.y);
      half2v h01a = __builtin_bit_cast(half2v, r0.z);
      half2v h23a = __builtin_bit_cast(half2v, r0.w);
      half2v t01b = __builtin_bit_cast(half2v, r1.x);
      half2v t23b = __builtin_bit_cast(half2v, r1.y);
      half2v h01b = __builtin_bit_cast(half2v, r1.z);
      half2v h23b = __builtin_bit_cast(half2v, r1.w);
      float p0 = fdot2(t23a, d23, fdot2(t01a, d01, 0.f)) * LOG2E;
      float p1 = fdot2(t23b, d23, fdot2(t01b, d01, 0.f)) * LOG2E;
      rowsum16x2(p0, p1);
      float wf0 = a0 + bfd;
      wf0 = (wf0 > 0.f) ? wf0 : NEG_SLOPE * wf0;
      float wf1 = a1 + bfd;
      wf1 = (wf1 > 0.f) ? wf1 : NEG_SLOPE * wf1;
      if (i + 1 >= end) { p1 = -1e30f; wf1 = -1e30f; }  // tail edge -> exp2=0
      float ef0 = fexp2(wf0), ef1 = fexp2(wf1);
      sf += ef0 + ef1;
      zf0 = fmaf((float)h01b[0], ef1, fmaf((float)h01a[0], ef0, zf0));
      zf1 = fmaf((float)h01b[1], ef1, fmaf((float)h01a[1], ef0, zf1));
      zf2 = fmaf((float)h23b[0], ef1, fmaf((float)h23a[0], ef0, zf2));
      zf3 = fmaf((float)h23b[1], ef1, fmaf((float)h23a[1], ef0, zf3));
      float pm0 = p0 - mt;
      if (pm0 > 60.f) {                 // rare: first edge / new-max-by-far
        float sc = fexp2(-pm0);         // ==0 when mt==NEG_BIG
        st *= sc;
        zt0 *= sc; zt1 *= sc; zt2 *= sc; zt3 *= sc;
        mt = p0; pm0 = 0.f;
      }
      float et0 = fexp2(pm0);
      st += et0;
      zt0 = fmaf((float)h01a[0], et0, zt0);
      zt1 = fmaf((float)h01a[1], et0, zt1);
      zt2 = fmaf((float)h23a[0], et0, zt2);
      zt3 = fmaf((float)h23a[1], et0, zt3);
      float pm1 = p1 - mt;
      if (pm1 > 60.f) {
        float sc = fexp2(-pm1);
        st *= sc;
        zt0 *= sc; zt1 *= sc; zt2 *= sc; zt3 *= sc;
        mt = p1; pm1 = 0.f;
      }
      float et1 = fexp2(pm1);
      st += et1;
      zt0 = fmaf((float)h01b[0], et1, zt0);
      zt1 = fmaf((float)h01b[1], et1, zt1);
      zt2 = fmaf((float)h23b[0], et1, zt2);
      zt3 = fmaf((float)h23b[1], et1, zt3);
      r0 = rn0; a0 = an0; r1 = rn1; a1 = an1;
      s2 = s4;  s3 = s5;
    }
    float4 zv = make_float4(0.f, 0.f, 0.f, 0.f);
    if (end > beg) {
      float rf = ETA / sf, rt = (1.f - ETA) / st;
      zv.x = rf * zf0 + rt * zt0;
      zv.y = rf * zf1 + rt * zt1;
      zv.z = rf * zf2 + rt * zt2;
      zv.w = rf * zf3 + rt * zt3;
    }
    uint2 zo;
    zo.x = pack2(zv.x, zv.y);
    zo.y = pack2(zv.z, zv.w);
    ((uint2*)(z + (size_t)d * 64))[q] = zo;
  }
}

// out = z @ W^T + b via MFMA. One wave per 16-node tile, all 64 output cols.
// W split into f16 hi+lo so accuracy stays at f32-weight level.
#ifdef HAVE_MFMA16
__launch_bounds__(256)
__global__ void k_out_gemm(const unsigned short* __restrict__ z,
                           const float* __restrict__ W,
                           const float* __restrict__ b, float* __restrict__ out, int n) {
  int l = threadIdx.x & 63;
  int wv = threadIdx.x >> 6;
  int c16 = l & 15;   // A-row / B-col / D-col within tile
  int seg = l >> 4;   // k-segment selector
  half8v bh[4][2], bl[4][2];
#pragma unroll
  for (int jt = 0; jt < 4; ++jt) {
    const float* wr = W + (size_t)(jt * 16 + c16) * 64 + seg * 8;
#pragma unroll
    for (int ks = 0; ks < 2; ++ks) {
      const float* wk = wr + ks * 32;
#pragma unroll
      for (int e = 0; e < 8; ++e) {
        float wvv = wk[e];
        _Float16 hi = (_Float16)wvv;
        bh[jt][ks][e] = hi;
        bl[jt][ks][e] = (_Float16)(wvv - (float)hi);
      }
    }
  }
  float bias0 = b[c16], bias1 = b[16 + c16], bias2 = b[32 + c16], bias3 = b[48 + c16];
  const half8v* z8 = (const half8v*)z;
  int tiles = (n + 15) >> 4;
  int nw = (int)gridDim.x * 4;
  for (int t = (int)blockIdx.x * 4 + wv; t < tiles; t += nw) {
    int base = t << 4;
    int arow = base + c16;
    size_t zi = (size_t)(arow < n ? arow : n - 1) * 8 + seg;
    half8v a0 = z8[zi];
    half8v a1 = z8[zi + 4];
    f32x4v acc0 = {bias0, bias0, bias0, bias0};
    f32x4v acc1 = {bias1, bias1, bias1, bias1};
    f32x4v acc2 = {bias2, bias2, bias2, bias2};
    f32x4v acc3 = {bias3, bias3, bias3, bias3};
    acc0 = __builtin_amdgcn_mfma_f32_16x16x32_f16(a0, bh[0][0], acc0, 0, 0, 0);
    acc1 = __builtin_amdgcn_mfma_f32_16x16x32_f16(a0, bh[1][0], acc1, 0, 0, 0);
    acc2 = __builtin_amdgcn_mfma_f32_16x16x32_f16(a0, bh[2][0], acc2, 0, 0, 0);
    acc3 = __builtin_amdgcn_mfma_f32_16x16x32_f16(a0, bh[3][0], acc3, 0, 0, 0);
    acc0 = __builtin_amdgcn_mfma_f32_16x16x32_f16(a1, bh[0][1], acc0, 0, 0, 0);
    acc1 = __builtin_amdgcn_mfma_f32_16x16x32_f16(a1, bh[1][1], acc1, 0, 0, 0);
    acc2 = __builtin_amdgcn_mfma_f32_16x16x32_f16(a1, bh[2][1], acc2, 0, 0, 0);
    acc3 = __builtin_amdgcn_mfma_f32_16x16x32_f16(a1, bh[3][1], acc3, 0, 0, 0);
    acc0 = __builtin_amdgcn_mfma_f32_16x16x32_f16(a0, bl[0][0], acc0, 0, 0, 0);
    acc1 = __builtin_amdgcn_mfma_f32_16x16x32_f16(a0, bl[1][0], acc1, 0, 0, 0);
    acc2 = __builtin_amdgcn_mfma_f32_16x16x32_f16(a0, bl[2][0], acc2, 0, 0, 0);
    acc3 = __builtin_amdgcn_mfma_f32_16x16x32_f16(a0, bl[3][0], acc3, 0, 0, 0);
    acc0 = __builtin_amdgcn_mfma_f32_16x16x32_f16(a1, bl[0][1], acc0, 0, 0, 0);
    acc1 = __builtin_amdgcn_mfma_f32_16x16x32_f16(a1, bl[1][1], acc1, 0, 0, 0);
    acc2 = __builtin_amdgcn_mfma_f32_16x16x32_f16(a1, bl[2][1], acc2, 0, 0, 0);
    acc3 = __builtin_amdgcn_mfma_f32_16x16x32_f16(a1, bl[3][1], acc3, 0, 0, 0);
#pragma unroll
    for (int r = 0; r < 4; ++r) {
      int nrow = base + seg * 4 + r;
      if (nrow < n) {
        float* o = out + (size_t)nrow * 64 + c16;
        o[0]  = acc0[r];
        o[16] = acc1[r];
        o[32] = acc2[r];
        o[48] = acc3[r];
      }
    }
  }
}
#else
__launch_bounds__(256)
__global__ void k_out_gemm(const unsigned short* __restrict__ z,
                           const float* __restrict__ W,
                           const float* __restrict__ b, float* __restrict__ out, int n) {
  int t = threadIdx.x;
  int j = t & 63, nl = t >> 6;
  float wreg[64];
#pragma unroll
  for (int i = 0; i < 16; ++i)
    ((float4*)wreg)[i] = ((const float4*)(W + (size_t)j * 64))[i];
  float bias = b[j];
  int stride = gridDim.x * 4;
  for (int node = blockIdx.x * 4 + nl; node < n; node += stride) {
    float zv = (float)__builtin_bit_cast(_Float16, z[(size_t)node * 64 + j]);
    float acc = bias;
#pragma unroll
    for (int k = 0; k < 64; ++k)
      acc += __shfl(zv, k) * wreg[k];
    out[(size_t)node * 64 + j] = acc;
  }
}
#endif

extern "C" void kernel_launch(void* const* d_in, const int* in_sizes, int n_in,
                              void* d_out, int out_size, void* d_ws, size_t ws_size,
                              hipStream_t stream) {
  const float* h   = (const float*)d_in[0];
  const float* tax = (const float*)d_in[1];
  const int*   src = (const int*)d_in[2];
  const int*   dst = (const int*)d_in[3];
  const float* whw = (const float*)d_in[4];
  const float* Ww  = (const float*)d_in[5];
  const float* Wb  = (const float*)d_in[6];
  float* out = (float*)d_out;
  int n  = in_sizes[0] / 64;
  int ne = in_sizes[2];
  int nb = (n + 63) >> 6;   // 64-dst buckets (1563 for n=100k); nb <= NBMAX

  // Workspace layout (4-byte words; rec aligned to 16 B):
  float* af   = (float*)d_ws;               // n
  float* bf   = af + n;                     // n
  int*   gcur = (int*)(bf + n);             // NBMAX
  size_t w = (size_t)(2 * n) + NBMAX;
  w = (w + 3) & ~(size_t)3;                 // 16B-align
  unsigned short* z = (unsigned short*)((int*)d_ws + w);  // n*64 u16
  uint4* rec = (uint4*)(z + (size_t)n * 64);              // n*16 uint4
  // Packed sort plane aliases z (consumed by k_fused's sort phase before
  // any z write: per block, pck segment is read fully before gather writes):
  int* pck = (int*)z;                       // nb*CAP*4B (9.6MB) <= n*128B

  int nprep = (n * 16 + 255) / 256;
  int npart = (ne + PCHUNK - 1) / PCHUNK;
  int bg    = (((n + 15) >> 4) + 3) / 4;    // out_gemm: one tile per wave

  hipMemsetAsync(gcur, 0, (size_t)nb * sizeof(int), stream);
  k_prep_part<<<npart + nprep, 256, 0, stream>>>(h, tax, whw, af, bf, rec,
                                                 src, dst, gcur, pck, n, ne, nb, npart);
  k_fused<<<nb, 256, 0, stream>>>(rec, af, bf, gcur, pck, z, n);
  k_out_gemm<<<bg, 256, 0, stream>>>(z, Ww, Wb, out, n);
}